// Round 1
// baseline (3227.625 us; speedup 1.0000x reference)
//
#include <hip/hip_runtime.h>

// RoIHeads postprocess: decode + softmax + filter + batched greedy NMS.
// B=8 images, N=8192 proposals, C=91 classes (class 0 = background dropped).
#define BIMG 8
#define NPROP 8192
#define NCLS 91
#define WIMG 800.0f
#define HIMG 800.0f
#define SCORE_T 0.05f
#define NMS_T 0.5f
#define NDET 100
// float(np.log(1000.0/16.0)) rounded to f32
#define CLIPV 4.135166556742356f

// ---------------- kernel 0: zero the per-image candidate counters ----------
__global__ void zero_cnt_kernel(int* cnt) {
    if (threadIdx.x < 64) cnt[threadIdx.x] = 0;
}

// ---------------- kernel 1: decode + softmax + filter + compact ------------
// One block (128 threads) per (b, n) row. Threads 0..90 own classes.
__global__ __launch_bounds__(128)
void decode_kernel(const float* __restrict__ logits,
                   const float* __restrict__ creg,
                   const float* __restrict__ props,
                   float* __restrict__ X1, float* __restrict__ Y1,
                   float* __restrict__ X2, float* __restrict__ Y2,
                   float* __restrict__ SS, unsigned char* __restrict__ LL,
                   int* __restrict__ cnt, int cap)
{
    const int row = blockIdx.x;            // b*NPROP + n
    const int b = row / NPROP;
    const int tid = threadIdx.x;
    __shared__ float sm[128];

    const float* lrow = logits + (size_t)row * NCLS;
    float l = (tid < NCLS) ? lrow[tid] : -3.4e38f;

    // block max
    sm[tid] = l; __syncthreads();
    for (int off = 64; off > 0; off >>= 1) {
        if (tid < off) sm[tid] = fmaxf(sm[tid], sm[tid + off]);
        __syncthreads();
    }
    float m = sm[0]; __syncthreads();

    float e = (tid < NCLS) ? expf(l - m) : 0.0f;
    sm[tid] = e; __syncthreads();
    for (int off = 64; off > 0; off >>= 1) {
        if (tid < off) sm[tid] += sm[tid + off];
        __syncthreads();
    }
    const float denom = sm[0];
    const float score = e / denom;

    if (tid >= 1 && tid < NCLS && score > SCORE_T) {
        // proposal geometry (redundant per-thread load; L1 broadcast)
        const float* p = props + (size_t)row * 4;
        const float px1 = p[0], py1 = p[1], px2 = p[2], py2 = p[3];
        const float w = px2 - px1, h = py2 - py1;
        const float cx = px1 + 0.5f * w, cy = py1 + 0.5f * h;

        const float* cd = creg + ((size_t)row * NCLS + tid) * 4;
        const float dx = cd[0] / 10.0f;
        const float dy = cd[1] / 10.0f;
        const float dw = fminf(cd[2] / 5.0f, CLIPV);
        const float dh = fminf(cd[3] / 5.0f, CLIPV);
        const float pcx = dx * w + cx, pcy = dy * h + cy;
        const float pw = expf(dw) * w, ph = expf(dh) * h;
        float bx1 = pcx - 0.5f * pw, by1 = pcy - 0.5f * ph;
        float bx2 = pcx + 0.5f * pw, by2 = pcy + 0.5f * ph;
        bx1 = fminf(fmaxf(bx1, 0.0f), WIMG);
        by1 = fminf(fmaxf(by1, 0.0f), HIMG);
        bx2 = fminf(fmaxf(bx2, 0.0f), WIMG);
        by2 = fminf(fmaxf(by2, 0.0f), HIMG);
        const float bw = bx2 - bx1, bh = by2 - by1;
        if (bw >= 1.0f && bh >= 1.0f) {
            const int k = atomicAdd(&cnt[b], 1);
            if (k < cap) {
                const size_t idx = (size_t)b * cap + k;
                X1[idx] = bx1; Y1[idx] = by1;
                X2[idx] = bx2; Y2[idx] = by2;
                SS[idx] = score;
                LL[idx] = (unsigned char)tid;   // label = class index 1..90
            }
        }
    }
}

// ---------------- kernel 2: greedy batched NMS, one block per image --------
// Fused pass per iteration: suppress(previous top) while computing argmax.
__global__ __launch_bounds__(1024)
void nms_kernel(const float* __restrict__ X1, const float* __restrict__ Y1,
                const float* __restrict__ X2, const float* __restrict__ Y2,
                float* __restrict__ SS, const unsigned char* __restrict__ LL,
                const int* __restrict__ cnt, float* __restrict__ out, int cap)
{
    const int b = blockIdx.x;
    const int tid = threadIdx.x;
    const int T = 1024;
    int K = cnt[b]; if (K > cap) K = cap;
    const size_t base = (size_t)b * cap;
    float* S = SS + base;
    const float* x1 = X1 + base; const float* y1 = Y1 + base;
    const float* x2 = X2 + base; const float* y2 = Y2 + base;
    const unsigned char* lb = LL + base;

    __shared__ float sv[1024];
    __shared__ int   si[1024];
    __shared__ float pbox[4];
    __shared__ int   plbl;
    __shared__ int   phas;
    if (tid == 0) phas = 0;
    __syncthreads();

    const int OB = 0, OS = BIMG * NDET * 4, OL = OS + BIMG * NDET,
              OV = OL + BIMG * NDET;

    for (int it = 0; it < NDET; ++it) {
        const int hasP = phas;
        float tx1 = 0, ty1 = 0, tx2 = 0, ty2 = 0, ta = 0;
        int tl = -1;
        if (hasP) {
            tl = plbl;
            const float off = (float)tl * 801.0f;   // max(H,W)+1, per-class offset
            tx1 = pbox[0] + off; ty1 = pbox[1] + off;
            tx2 = pbox[2] + off; ty2 = pbox[3] + off;
            ta = (tx2 - tx1) * (ty2 - ty1);
        }

        float best = 0.0f; int bi = -1;
        for (int i = tid; i < K; i += T) {
            float s = S[i];
            if (s > 0.0f && hasP) {
                const int l = lb[i];
                if (l == tl) {
                    // exact replication of reference IoU in OFFSET space
                    const float off = (float)tl * 801.0f;
                    const float nx1 = x1[i] + off, ny1 = y1[i] + off;
                    const float nx2 = x2[i] + off, ny2 = y2[i] + off;
                    const float ltx = fmaxf(tx1, nx1), lty = fmaxf(ty1, ny1);
                    const float rbx = fminf(tx2, nx2), rby = fminf(ty2, ny2);
                    const float iw = fmaxf(rbx - ltx, 0.0f);
                    const float ih = fmaxf(rby - lty, 0.0f);
                    const float inter = iw * ih;
                    const float a2 = (nx2 - nx1) * (ny2 - ny1);
                    const float iou = inter / (ta + a2 - inter + 1e-9f);
                    if (iou > NMS_T) { S[i] = -1.0f; s = -1.0f; }
                }
            }
            if (s > best) { best = s; bi = i; }  // strict > keeps smallest index on ties
        }
        sv[tid] = best; si[tid] = bi;
        __syncthreads();
        for (int off = 512; off > 0; off >>= 1) {
            if (tid < off) {
                const float v2 = sv[tid + off]; const int i2 = si[tid + off];
                if (v2 > sv[tid] ||
                    (v2 == sv[tid] && i2 >= 0 && (si[tid] < 0 || i2 < si[tid]))) {
                    sv[tid] = v2; si[tid] = i2;
                }
            }
            __syncthreads();
        }
        const float top = sv[0];
        const int ti = si[0];

        if (top <= 0.0f) {
            // exhausted: zero-fill remaining detection slots and quit
            for (int j = it + tid; j < NDET; j += T) {
                const int o = b * NDET + j;
                out[OB + o * 4 + 0] = 0.0f; out[OB + o * 4 + 1] = 0.0f;
                out[OB + o * 4 + 2] = 0.0f; out[OB + o * 4 + 3] = 0.0f;
                out[OS + o] = 0.0f; out[OL + o] = 0.0f; out[OV + o] = 0.0f;
            }
            break;
        }

        if (tid == 0) {
            const int o = b * NDET + it;
            out[OB + o * 4 + 0] = x1[ti]; out[OB + o * 4 + 1] = y1[ti];
            out[OB + o * 4 + 2] = x2[ti]; out[OB + o * 4 + 3] = y2[ti];
            out[OS + o] = top;
            out[OL + o] = (float)lb[ti];
            out[OV + o] = 1.0f;
            pbox[0] = x1[ti]; pbox[1] = y1[ti];
            pbox[2] = x2[ti]; pbox[3] = y2[ti];
            plbl = lb[ti]; phas = 1;
        }
        __syncthreads();   // publish pbox/plbl/phas; also guards sv/si reuse
    }
}

extern "C" void kernel_launch(void* const* d_in, const int* in_sizes, int n_in,
                              void* d_out, int out_size, void* d_ws, size_t ws_size,
                              hipStream_t stream) {
    const float* logits = (const float*)d_in[0];   // [B,N,91]
    const float* creg   = (const float*)d_in[1];   // [B,N,364]
    const float* props  = (const float*)d_in[2];   // [B,N,4]
    float* out = (float*)d_out;                    // 3200 + 800 + 800 + 800

    // workspace layout: [0,1024) counters; then 5 float arrays + 1 byte array,
    // each B*cap elements.
    const size_t hdr = 1024;
    size_t usable = (ws_size > hdr) ? (ws_size - hdr) : 0;
    long cap = (long)(usable / ((size_t)BIMG * 21));  // 5*4 + 1 bytes per slot
    if (cap > (long)NPROP * (NCLS - 1)) cap = (long)NPROP * (NCLS - 1);
    cap &= ~511L;                                     // keep arrays aligned-ish
    if (cap < 512) cap = 512;                         // degenerate ws guard

    int* cnt = (int*)d_ws;
    float* X1 = (float*)((char*)d_ws + hdr);
    float* Y1 = X1 + (size_t)BIMG * cap;
    float* X2 = Y1 + (size_t)BIMG * cap;
    float* Y2 = X2 + (size_t)BIMG * cap;
    float* SS = Y2 + (size_t)BIMG * cap;
    unsigned char* LL = (unsigned char*)(SS + (size_t)BIMG * cap);

    zero_cnt_kernel<<<1, 64, 0, stream>>>(cnt);
    decode_kernel<<<BIMG * NPROP, 128, 0, stream>>>(
        logits, creg, props, X1, Y1, X2, Y2, SS, LL, cnt, (int)cap);
    nms_kernel<<<BIMG, 1024, 0, stream>>>(
        X1, Y1, X2, Y2, SS, LL, cnt, out, (int)cap);
}

// Round 2
// 635.372 us; speedup vs baseline: 5.0799x; 5.0799x over previous
//
#include <hip/hip_runtime.h>

// RoIHeads postprocess: decode + softmax + filter + per-class greedy NMS + merge.
// B=8 images, N=8192 proposals, C=91 classes (class 0 = background dropped).
#define BIMG 8
#define NPROP 8192
#define NCLS 91
#define WIMG 800.0f
#define HIMG 800.0f
#define SCORE_T 0.05f
#define NMS_T 0.5f
#define NDET 100
#define CLIPV 4.135166556742356f   // float(log(1000/16))
#define CNT_STRIDE 16              // 64B-padded per-(b,c) counters
#define NSURV 100                  // per-class survivor cap

__device__ __forceinline__ unsigned long long packkey(float s, int idx) {
    // s > 0 always; higher score wins, then smaller flat index wins.
    return ((unsigned long long)__float_as_uint(s) << 32) |
           (unsigned long long)(0xFFFFFFFFu - (unsigned int)idx);
}

// ---------------- kernel 0: zero counters (cnt + scnt, contiguous) ---------
__global__ void zero_kernel(int* p, int n) {
    int i = blockIdx.x * blockDim.x + threadIdx.x;
    if (i < n) p[i] = 0;
}

// ---------------- kernel 1: decode + softmax + filter, bin by (b,c) --------
// One wave (64 lanes) per proposal row. Lane l owns classes {l, l+64}.
__global__ __launch_bounds__(256)
void decode_kernel(const float* __restrict__ logits,
                   const float* __restrict__ creg,
                   const float* __restrict__ props,
                   float* __restrict__ CX1, float* __restrict__ CY1,
                   float* __restrict__ CX2, float* __restrict__ CY2,
                   float* __restrict__ CS, int* __restrict__ CIDX,
                   int* __restrict__ cnt, int capC)
{
    const int wave = blockIdx.x * 4 + (threadIdx.x >> 6);
    const int lane = threadIdx.x & 63;
    const int row = wave;                 // 0 .. B*N-1
    const int b = row >> 13;              // /NPROP
    const int n = row & (NPROP - 1);

    const float* lrow = logits + (size_t)row * NCLS;
    const float l0 = lrow[lane];                                   // lane<91 always
    const float l1 = (lane + 64 < NCLS) ? lrow[lane + 64] : -3.4e38f;

    // max (order-independent)
    float m = fmaxf(l0, l1);
    for (int mm = 32; mm > 0; mm >>= 1) m = fmaxf(m, __shfl_xor(m, mm));

    const float e0 = expf(l0 - m);
    const float e1 = (lane + 64 < NCLS) ? expf(l1 - m) : 0.0f;

    // sum: butterfly == balanced binary tree over 128 slots; broadcast lane 0's
    // association so every class divides by the IDENTICAL denom (matches the
    // round-1 LDS-tree bit-for-bit).
    float s = e0 + e1;
    for (int mm = 32; mm > 0; mm >>= 1) s += __shfl_xor(s, mm);
    const float denom = __shfl(s, 0);

    // proposal geometry (uniform address -> scalar loads)
    const float* p = props + (size_t)row * 4;
    const float px1 = p[0], py1 = p[1], px2 = p[2], py2 = p[3];
    const float w = px2 - px1, h = py2 - py1;
    const float cx = px1 + 0.5f * w, cy = py1 + 0.5f * h;

    for (int half = 0; half < 2; ++half) {
        const int c = lane + half * 64;
        if (c < 1 || c >= NCLS) continue;
        const float score = (half ? e1 : e0) / denom;
        if (!(score > SCORE_T)) continue;

        const float* cd = creg + ((size_t)row * NCLS + c) * 4;
        const float dx = cd[0] / 10.0f;
        const float dy = cd[1] / 10.0f;
        const float dw = fminf(cd[2] / 5.0f, CLIPV);
        const float dh = fminf(cd[3] / 5.0f, CLIPV);
        const float pcx = dx * w + cx, pcy = dy * h + cy;
        const float pw = expf(dw) * w, ph = expf(dh) * h;
        float bx1 = pcx - 0.5f * pw, by1 = pcy - 0.5f * ph;
        float bx2 = pcx + 0.5f * pw, by2 = pcy + 0.5f * ph;
        bx1 = fminf(fmaxf(bx1, 0.0f), WIMG);
        by1 = fminf(fmaxf(by1, 0.0f), HIMG);
        bx2 = fminf(fmaxf(bx2, 0.0f), WIMG);
        by2 = fminf(fmaxf(by2, 0.0f), HIMG);
        if ((bx2 - bx1) >= 1.0f && (by2 - by1) >= 1.0f) {
            const int bc = b * NCLS + c;
            const int k = atomicAdd(&cnt[bc * CNT_STRIDE], 1);
            if (k < capC) {
                const size_t o = (size_t)bc * capC + k;
                CX1[o] = bx1; CY1[o] = by1; CX2[o] = bx2; CY2[o] = by2;
                CS[o] = score;
                CIDX[o] = n * (NCLS - 1) + (c - 1);   // reference flat index
            }
        }
    }
}

// ---------------- kernel 2: per-(image,class) greedy NMS, one wave each ----
__global__ __launch_bounds__(64)
void nms_class_kernel(const float* __restrict__ CX1, const float* __restrict__ CY1,
                      const float* __restrict__ CX2, const float* __restrict__ CY2,
                      const float* __restrict__ CS, const int* __restrict__ CIDX,
                      const int* __restrict__ cnt,
                      float* __restrict__ SX1, float* __restrict__ SY1,
                      float* __restrict__ SX2, float* __restrict__ SY2,
                      float* __restrict__ SS, int* __restrict__ SIDX,
                      int* __restrict__ scnt, int capC)
{
    const int bc = blockIdx.x;           // b*91 + c
    const int c = bc % NCLS;
    const int lane = threadIdx.x;
    if (c == 0) { if (lane == 0) scnt[bc] = 0; return; }

    int K = cnt[bc * CNT_STRIDE]; if (K > capC) K = capC;

    __shared__ float lx1[1024], ly1[1024], lx2[1024], ly2[1024], ls[1024];
    __shared__ int   lidx[1024];
    __shared__ float wbox[4];

    const size_t base = (size_t)bc * capC;
    for (int i = lane; i < K; i += 64) {
        lx1[i] = CX1[base + i]; ly1[i] = CY1[base + i];
        lx2[i] = CX2[base + i]; ly2[i] = CY2[base + i];
        ls[i]  = CS[base + i];  lidx[i] = CIDX[base + i];
    }

    const float off = (float)c * 801.0f;     // max(H,W)+1 per-class offset
    int nsel = 0;
    for (int it = 0; it < NSURV; ++it) {
        __syncthreads();
        // argmax by (score, -idx)
        unsigned long long mk = 0ull;
        for (int i = lane; i < K; i += 64) {
            const float sv = ls[i];
            if (sv > 0.0f) {
                const unsigned long long k = packkey(sv, lidx[i]);
                if (k > mk) mk = k;
            }
        }
        for (int mm = 32; mm > 0; mm >>= 1) {
            const unsigned long long o = __shfl_xor(mk, mm);
            if (o > mk) mk = o;
        }
        if (mk == 0ull) break;

        // unique winner lane records survivor + broadcasts its box
        for (int i = lane; i < K; i += 64) {
            const float sv = ls[i];
            if (sv > 0.0f && packkey(sv, lidx[i]) == mk) {
                const int sb = bc * NSURV + nsel;
                SX1[sb] = lx1[i]; SY1[sb] = ly1[i];
                SX2[sb] = lx2[i]; SY2[sb] = ly2[i];
                SS[sb] = sv; SIDX[sb] = lidx[i];
                wbox[0] = lx1[i]; wbox[1] = ly1[i];
                wbox[2] = lx2[i]; wbox[3] = ly2[i];
            }
        }
        __syncthreads();

        // suppress in OFFSET space, replicating reference IoU arithmetic
        const float tx1 = wbox[0] + off, ty1 = wbox[1] + off;
        const float tx2 = wbox[2] + off, ty2 = wbox[3] + off;
        const float ta = (tx2 - tx1) * (ty2 - ty1);
        for (int i = lane; i < K; i += 64) {
            if (ls[i] > 0.0f) {
                const float nx1 = lx1[i] + off, ny1 = ly1[i] + off;
                const float nx2 = lx2[i] + off, ny2 = ly2[i] + off;
                const float ltx = fmaxf(tx1, nx1), lty = fmaxf(ty1, ny1);
                const float rbx = fminf(tx2, nx2), rby = fminf(ty2, ny2);
                const float iw = fmaxf(rbx - ltx, 0.0f);
                const float ih = fmaxf(rby - lty, 0.0f);
                const float inter = iw * ih;
                const float a2 = (nx2 - nx1) * (ny2 - ny1);
                const float iou = inter / (ta + a2 - inter + 1e-9f);
                if (iou > NMS_T) ls[i] = -1.0f;   // includes self (IoU ~ 1)
            }
        }
        ++nsel;
    }
    __syncthreads();
    if (lane == 0) scnt[bc] = nsel;
}

// ---------------- kernel 3: 90-way merge of per-class sorted survivors -----
__global__ __launch_bounds__(64)
void merge_kernel(const float* __restrict__ SX1, const float* __restrict__ SY1,
                  const float* __restrict__ SX2, const float* __restrict__ SY2,
                  const float* __restrict__ SS, const int* __restrict__ SIDX,
                  const int* __restrict__ scnt, float* __restrict__ out)
{
    const int b = blockIdx.x;
    const int lane = threadIdx.x;
    __shared__ int heads[NCLS];
    __shared__ int sc[NCLS];
    for (int i = lane; i < NCLS; i += 64) {
        heads[i] = 0;
        sc[i] = scnt[b * NCLS + i];
    }
    __syncthreads();

    const int c1 = 1 + lane;              // classes 1..64
    const int c2 = 65 + lane;             // classes 65..90 (lane<=25)
    const int OB = 0, OS = BIMG * NDET * 4, OL = OS + BIMG * NDET,
              OV = OL + BIMG * NDET;

    int step = 0;
    for (; step < NDET; ++step) {
        unsigned long long k1 = 0ull, k2 = 0ull;
        const int h1 = heads[c1];
        if (h1 < sc[c1]) {
            const int sb = (b * NCLS + c1) * NSURV + h1;
            k1 = packkey(SS[sb], SIDX[sb]);
        }
        if (c2 < NCLS) {
            const int h2 = heads[c2];
            if (h2 < sc[c2]) {
                const int sb = (b * NCLS + c2) * NSURV + h2;
                k2 = packkey(SS[sb], SIDX[sb]);
            }
        }
        unsigned long long mk = (k1 > k2) ? k1 : k2;
        for (int mm = 32; mm > 0; mm >>= 1) {
            const unsigned long long o = __shfl_xor(mk, mm);
            if (o > mk) mk = o;
        }
        if (mk == 0ull) break;

        if (k1 == mk || k2 == mk) {       // unique winner (idx unique)
            const int c = (k1 == mk) ? c1 : c2;
            const int sb = (b * NCLS + c) * NSURV + heads[c];
            const int o = b * NDET + step;
            out[OB + o * 4 + 0] = SX1[sb]; out[OB + o * 4 + 1] = SY1[sb];
            out[OB + o * 4 + 2] = SX2[sb]; out[OB + o * 4 + 3] = SY2[sb];
            out[OS + o] = SS[sb];
            out[OL + o] = (float)c;
            out[OV + o] = 1.0f;
            heads[c]++;
        }
        __syncthreads();
    }
    // zero-fill exhausted slots
    for (int j = step + lane; j < NDET; j += 64) {
        const int o = b * NDET + j;
        out[OB + o * 4 + 0] = 0.0f; out[OB + o * 4 + 1] = 0.0f;
        out[OB + o * 4 + 2] = 0.0f; out[OB + o * 4 + 3] = 0.0f;
        out[OS + o] = 0.0f; out[OL + o] = 0.0f; out[OV + o] = 0.0f;
    }
}

extern "C" void kernel_launch(void* const* d_in, const int* in_sizes, int n_in,
                              void* d_out, int out_size, void* d_ws, size_t ws_size,
                              hipStream_t stream) {
    const float* logits = (const float*)d_in[0];   // [B,N,91]
    const float* creg   = (const float*)d_in[1];   // [B,N,364]
    const float* props  = (const float*)d_in[2];   // [B,N,4]
    float* out = (float*)d_out;                    // 3200+800+800+800 floats

    // ---- workspace layout ----
    // [0)            cnt  : 8*91*16 ints (64B-padded counters)     46592 B
    // [46592)        scnt : 8*91 ints                               2912 B
    // [49504)        survivors: 6 arrays x (8*91*100) x 4B       1747200 B
    // [1796704)      class lists: 6 arrays x (8*91*capC) x 4B
    const int nCnt = BIMG * NCLS * CNT_STRIDE;          // 11648
    const int nZero = nCnt + BIMG * NCLS;               // + scnt = 12376
    int* cnt = (int*)d_ws;
    int* scnt = cnt + nCnt;

    const size_t survSlots = (size_t)BIMG * NCLS * NSURV;   // 72800
    float* SX1 = (float*)((char*)d_ws + 49504);
    float* SY1 = SX1 + survSlots;
    float* SX2 = SY1 + survSlots;
    float* SY2 = SX2 + survSlots;
    float* SS  = SY2 + survSlots;
    int*   SIDX = (int*)(SS + survSlots);

    const size_t clBase = 49504 + survSlots * 6 * 4;         // 1,796,704
    long capC = 256;
    if (ws_size > clBase) {
        capC = (long)((ws_size - clBase) / ((size_t)BIMG * NCLS * 24));
        capC &= ~63L;
        if (capC < 256) capC = 256;
        if (capC > 1024) capC = 1024;
    }
    const size_t clSlots = (size_t)BIMG * NCLS * capC;
    float* CX1 = (float*)((char*)d_ws + clBase);
    float* CY1 = CX1 + clSlots;
    float* CX2 = CY1 + clSlots;
    float* CY2 = CX2 + clSlots;
    float* CS  = CY2 + clSlots;
    int*   CIDX = (int*)(CS + clSlots);

    zero_kernel<<<(nZero + 255) / 256, 256, 0, stream>>>(cnt, nZero);
    decode_kernel<<<BIMG * NPROP / 4, 256, 0, stream>>>(
        logits, creg, props, CX1, CY1, CX2, CY2, CS, CIDX, cnt, (int)capC);
    nms_class_kernel<<<BIMG * NCLS, 64, 0, stream>>>(
        CX1, CY1, CX2, CY2, CS, CIDX, cnt,
        SX1, SY1, SX2, SY2, SS, SIDX, scnt, (int)capC);
    merge_kernel<<<BIMG, 64, 0, stream>>>(
        SX1, SY1, SX2, SY2, SS, SIDX, scnt, out);
}

// Round 3
// 492.070 us; speedup vs baseline: 6.5593x; 1.2912x over previous
//
#include <hip/hip_runtime.h>

// RoIHeads postprocess: decode + softmax + filter + per-class NMS (sort +
// pairwise suppression matrix + bitmask scan) + k-way merge.
// B=8 images, N=8192 proposals, C=91 classes (class 0 = background dropped).
#define BIMG 8
#define NPROP 8192
#define NCLS 91
#define WIMG 800.0f
#define HIMG 800.0f
#define SCORE_T 0.05f
#define NMS_T 0.5f
#define NDET 100
#define CLIPV 4.135166556742356f   // float(log(1000/16))
#define CNT_STRIDE 16              // 64B-padded per-(b,c) counters
#define NSURV 100                  // per-class survivor cap
#define MAXK 512                   // per-(b,c) candidate cap (measured ~215)
#define MCACHE 32                  // merge: cached survivor keys per class

__device__ __forceinline__ unsigned long long packkey(float s, int idx) {
    // s > 0 always; higher score wins, then smaller flat index wins.
    return ((unsigned long long)__float_as_uint(s) << 32) |
           (unsigned long long)(0xFFFFFFFFu - (unsigned int)idx);
}

// ---------------- kernel 0: zero counters (cnt + scnt, contiguous) ---------
__global__ void zero_kernel(int* p, int n) {
    int i = blockIdx.x * blockDim.x + threadIdx.x;
    if (i < n) p[i] = 0;
}

// ---------------- kernel 1: decode + softmax + filter, bin by (b,c) --------
// One wave (64 lanes) per proposal row. Lane l owns classes {l, l+64}.
__global__ __launch_bounds__(256)
void decode_kernel(const float* __restrict__ logits,
                   const float* __restrict__ creg,
                   const float* __restrict__ props,
                   float* __restrict__ CX1, float* __restrict__ CY1,
                   float* __restrict__ CX2, float* __restrict__ CY2,
                   float* __restrict__ CS, int* __restrict__ CIDX,
                   int* __restrict__ cnt, int capC)
{
    const int wave = blockIdx.x * 4 + (threadIdx.x >> 6);
    const int lane = threadIdx.x & 63;
    const int row = wave;                 // 0 .. B*N-1
    const int b = row >> 13;              // /NPROP
    const int n = row & (NPROP - 1);

    const float* lrow = logits + (size_t)row * NCLS;
    const float l0 = lrow[lane];                                   // lane<91 always
    const float l1 = (lane + 64 < NCLS) ? lrow[lane + 64] : -3.4e38f;

    float m = fmaxf(l0, l1);
    for (int mm = 32; mm > 0; mm >>= 1) m = fmaxf(m, __shfl_xor(m, mm));

    const float e0 = expf(l0 - m);
    const float e1 = (lane + 64 < NCLS) ? expf(l1 - m) : 0.0f;

    float s = e0 + e1;
    for (int mm = 32; mm > 0; mm >>= 1) s += __shfl_xor(s, mm);
    const float denom = __shfl(s, 0);

    const float* p = props + (size_t)row * 4;
    const float px1 = p[0], py1 = p[1], px2 = p[2], py2 = p[3];
    const float w = px2 - px1, h = py2 - py1;
    const float cx = px1 + 0.5f * w, cy = py1 + 0.5f * h;

    for (int half = 0; half < 2; ++half) {
        const int c = lane + half * 64;
        if (c < 1 || c >= NCLS) continue;
        const float score = (half ? e1 : e0) / denom;
        if (!(score > SCORE_T)) continue;

        const float* cd = creg + ((size_t)row * NCLS + c) * 4;
        const float dx = cd[0] / 10.0f;
        const float dy = cd[1] / 10.0f;
        const float dw = fminf(cd[2] / 5.0f, CLIPV);
        const float dh = fminf(cd[3] / 5.0f, CLIPV);
        const float pcx = dx * w + cx, pcy = dy * h + cy;
        const float pw = expf(dw) * w, ph = expf(dh) * h;
        float bx1 = pcx - 0.5f * pw, by1 = pcy - 0.5f * ph;
        float bx2 = pcx + 0.5f * pw, by2 = pcy + 0.5f * ph;
        bx1 = fminf(fmaxf(bx1, 0.0f), WIMG);
        by1 = fminf(fmaxf(by1, 0.0f), HIMG);
        bx2 = fminf(fmaxf(bx2, 0.0f), WIMG);
        by2 = fminf(fmaxf(by2, 0.0f), HIMG);
        if ((bx2 - bx1) >= 1.0f && (by2 - by1) >= 1.0f) {
            const int bc = b * NCLS + c;
            const int k = atomicAdd(&cnt[bc * CNT_STRIDE], 1);
            if (k < capC) {
                const size_t o = (size_t)bc * capC + k;
                CX1[o] = bx1; CY1[o] = by1; CX2[o] = bx2; CY2[o] = by2;
                CS[o] = score;
                CIDX[o] = n * (NCLS - 1) + (c - 1);   // reference flat index
            }
        }
    }
}

// ---------------- kernel 2: per-(image,class) NMS, one 256-thr block -------
// sort by key desc -> pairwise IoU suppression matrix -> bitmask greedy scan.
__global__ __launch_bounds__(256)
void nms_class_kernel(const float* __restrict__ CX1, const float* __restrict__ CY1,
                      const float* __restrict__ CX2, const float* __restrict__ CY2,
                      const float* __restrict__ CS, const int* __restrict__ CIDX,
                      const int* __restrict__ cnt,
                      float* __restrict__ SX1, float* __restrict__ SY1,
                      float* __restrict__ SX2, float* __restrict__ SY2,
                      float* __restrict__ SS, int* __restrict__ SIDX,
                      int* __restrict__ scnt, int capC)
{
    const int bc = blockIdx.x;           // b*91 + c
    const int c = bc % NCLS;
    const int tid = threadIdx.x;
    const int lane = tid & 63;
    const int wv = tid >> 6;

    int K = 0;
    if (c != 0) {
        K = cnt[bc * CNT_STRIDE];
        if (K > capC) K = capC;
        if (K > MAXK) K = MAXK;
    }
    if (K == 0) { if (tid == 0) scnt[bc] = 0; return; }

    __shared__ float bx1[MAXK], by1[MAXK], bx2[MAXK], by2[MAXK], bs[MAXK];
    __shared__ int bidx[MAXK];
    __shared__ unsigned long long keys[MAXK];
    __shared__ unsigned long long mask[MAXK * 8];   // 32KB; also scatter tmp
    __shared__ int wseq[NSURV];
    __shared__ int nselsh;

    const size_t base = (size_t)bc * capC;
    for (int i = tid; i < K; i += 256) {
        const float v0 = CX1[base + i], v1 = CY1[base + i];
        const float v2 = CX2[base + i], v3 = CY2[base + i];
        const float sv = CS[base + i];
        const int ix = CIDX[base + i];
        bx1[i] = v0; by1[i] = v1; bx2[i] = v2; by2[i] = v3;
        bs[i] = sv; bidx[i] = ix;
        keys[i] = packkey(sv, ix);
    }
    __syncthreads();

    // rank (unique keys -> exact descending order), scatter into tmp
    float* tf = (float*)mask;
    int*   ti = (int*)mask;
    for (int i = tid; i < K; i += 256) {
        const unsigned long long k = keys[i];
        int r = 0;
        for (int j = 0; j < K; ++j) r += (keys[j] > k) ? 1 : 0;
        tf[0 * MAXK + r] = bx1[i];
        tf[1 * MAXK + r] = by1[i];
        tf[2 * MAXK + r] = bx2[i];
        tf[3 * MAXK + r] = by2[i];
        tf[4 * MAXK + r] = bs[i];
        ti[5 * MAXK + r] = bidx[i];
    }
    __syncthreads();
    for (int i = tid; i < K; i += 256) {
        bx1[i] = tf[0 * MAXK + i]; by1[i] = tf[1 * MAXK + i];
        bx2[i] = tf[2 * MAXK + i]; by2[i] = tf[3 * MAXK + i];
        bs[i]  = tf[4 * MAXK + i]; bidx[i] = ti[5 * MAXK + i];
    }
    __syncthreads();

    // pairwise suppression matrix: bit (a, j) = IoU(box_a, box_j) > 0.5,
    // reference arithmetic in offset space. Wave wv owns column strip(s) w.
    const float off = (float)c * 801.0f;     // max(H,W)+1 per-class offset
    const int W = (K + 63) >> 6;
    for (int w = wv; w < W; w += 4) {
        const int j = (w << 6) + lane;
        const bool jv = (j < K);
        float jx1 = 0, jy1 = 0, jx2 = 0, jy2 = 0;
        if (jv) {
            jx1 = bx1[j] + off; jy1 = by1[j] + off;
            jx2 = bx2[j] + off; jy2 = by2[j] + off;
        }
        const float a2 = (jx2 - jx1) * (jy2 - jy1);
        for (int a = 0; a < K; ++a) {
            const float ax1 = bx1[a] + off, ay1 = by1[a] + off;
            const float ax2 = bx2[a] + off, ay2 = by2[a] + off;
            const float ta = (ax2 - ax1) * (ay2 - ay1);
            bool sup = false;
            if (jv) {
                const float ltx = fmaxf(ax1, jx1), lty = fmaxf(ay1, jy1);
                const float rbx = fminf(ax2, jx2), rby = fminf(ay2, jy2);
                const float iw = fmaxf(rbx - ltx, 0.0f);
                const float ih = fmaxf(rby - lty, 0.0f);
                const float inter = iw * ih;
                const float iou = inter / (ta + a2 - inter + 1e-9f);
                sup = iou > NMS_T;
            }
            const unsigned long long bal = __ballot(sup);
            if (lane == 0) mask[a * 8 + w] = bal;
        }
    }
    __syncthreads();

    // greedy bitmask scan (wave 0): next alive in sorted order IS the next
    // greedy selection; each iteration selects exactly one survivor.
    if (wv == 0) {
        unsigned long long aw = 0ull;
        if (lane < 8) {
            const int lo = lane << 6;
            if (K > lo) {
                const int nb = K - lo;
                aw = (nb >= 64) ? ~0ull : ((1ull << nb) - 1ull);
            }
        }
        int nsel = 0;
        while (nsel < NSURV) {
            int pos = 0x7fffffff;
            if (aw) pos = (lane << 6) + __builtin_ctzll(aw);
            for (int mm = 32; mm > 0; mm >>= 1)
                pos = min(pos, __shfl_xor(pos, mm));
            if (pos == 0x7fffffff) break;
            if (lane == 0) wseq[nsel] = pos;
            if (lane < 8) aw &= ~mask[(size_t)pos * 8 + lane];
            ++nsel;
        }
        if (lane == 0) nselsh = nsel;
    }
    __syncthreads();

    const int nsel = nselsh;
    for (int t = tid; t < nsel; t += 256) {
        const int a = wseq[t];
        const int sb = bc * NSURV + t;
        SX1[sb] = bx1[a]; SY1[sb] = by1[a];
        SX2[sb] = bx2[a]; SY2[sb] = by2[a];
        SS[sb] = bs[a]; SIDX[sb] = bidx[a];
    }
    if (tid == 0) scnt[bc] = nsel;
}

// ---------------- kernel 3: 90-way merge, keys cached in LDS ---------------
__global__ __launch_bounds__(256)
void merge_kernel(const float* __restrict__ SX1, const float* __restrict__ SY1,
                  const float* __restrict__ SX2, const float* __restrict__ SY2,
                  const float* __restrict__ SS, const int* __restrict__ SIDX,
                  const int* __restrict__ scnt, float* __restrict__ out)
{
    const int b = blockIdx.x;
    const int tid = threadIdx.x;
    const int lane = tid & 63;
    const int wv = tid >> 6;

    __shared__ unsigned long long kc[NCLS * MCACHE];  // 23.3KB
    __shared__ int scs[NCLS];
    __shared__ int wseq[NDET];                        // (c<<16)|head
    __shared__ int stepsh;

    for (int i = tid; i < NCLS; i += 256) scs[i] = scnt[b * NCLS + i];
    __syncthreads();
    for (int t = tid; t < NCLS * MCACHE; t += 256) {
        const int cc = t >> 5, h = t & (MCACHE - 1);
        unsigned long long k = 0ull;
        if (cc >= 1 && h < scs[cc]) {
            const int sb = (b * NCLS + cc) * NSURV + h;
            k = packkey(SS[sb], SIDX[sb]);
        }
        kc[t] = k;
    }
    __syncthreads();

    if (wv == 0) {
        const int c1 = 1 + lane;                      // classes 1..64
        const int c2 = 65 + lane;                     // classes 65..90
        const bool v2 = (c2 < NCLS);
        int h1 = 0, h2 = 0;
        const int s1 = scs[c1];
        const int s2 = v2 ? scs[c2] : 0;
        unsigned long long k1 = (s1 > 0) ? kc[c1 * MCACHE] : 0ull;
        unsigned long long k2 = (s2 > 0) ? kc[c2 * MCACHE] : 0ull;
        int step = 0;
        while (step < NDET) {
            unsigned long long mk = (k1 > k2) ? k1 : k2;
            for (int mm = 32; mm > 0; mm >>= 1) {
                const unsigned long long o = __shfl_xor(mk, mm);
                if (o > mk) mk = o;
            }
            if (mk == 0ull) break;
            if (k1 == mk) {                           // unique winner lane+slot
                wseq[step] = (c1 << 16) | h1;
                ++h1;
                k1 = (h1 < s1)
                     ? (h1 < MCACHE ? kc[c1 * MCACHE + h1]
                                    : packkey(SS[(b * NCLS + c1) * NSURV + h1],
                                              SIDX[(b * NCLS + c1) * NSURV + h1]))
                     : 0ull;
            } else if (k2 == mk) {
                wseq[step] = (c2 << 16) | h2;
                ++h2;
                k2 = (h2 < s2)
                     ? (h2 < MCACHE ? kc[c2 * MCACHE + h2]
                                    : packkey(SS[(b * NCLS + c2) * NSURV + h2],
                                              SIDX[(b * NCLS + c2) * NSURV + h2]))
                     : 0ull;
            }
            ++step;
        }
        if (lane == 0) stepsh = step;
    }
    __syncthreads();

    const int OB = 0, OS = BIMG * NDET * 4, OL = OS + BIMG * NDET,
              OV = OL + BIMG * NDET;
    const int step = stepsh;
    for (int t = tid; t < NDET; t += 256) {
        const int o = b * NDET + t;
        if (t < step) {
            const int cw = wseq[t] >> 16, h = wseq[t] & 0xFFFF;
            const int sb = (b * NCLS + cw) * NSURV + h;
            out[OB + o * 4 + 0] = SX1[sb]; out[OB + o * 4 + 1] = SY1[sb];
            out[OB + o * 4 + 2] = SX2[sb]; out[OB + o * 4 + 3] = SY2[sb];
            out[OS + o] = SS[sb];
            out[OL + o] = (float)cw;
            out[OV + o] = 1.0f;
        } else {
            out[OB + o * 4 + 0] = 0.0f; out[OB + o * 4 + 1] = 0.0f;
            out[OB + o * 4 + 2] = 0.0f; out[OB + o * 4 + 3] = 0.0f;
            out[OS + o] = 0.0f; out[OL + o] = 0.0f; out[OV + o] = 0.0f;
        }
    }
}

extern "C" void kernel_launch(void* const* d_in, const int* in_sizes, int n_in,
                              void* d_out, int out_size, void* d_ws, size_t ws_size,
                              hipStream_t stream) {
    const float* logits = (const float*)d_in[0];   // [B,N,91]
    const float* creg   = (const float*)d_in[1];   // [B,N,364]
    const float* props  = (const float*)d_in[2];   // [B,N,4]
    float* out = (float*)d_out;                    // 3200+800+800+800 floats

    const int nCnt = BIMG * NCLS * CNT_STRIDE;          // 11648
    const int nZero = nCnt + BIMG * NCLS;               // + scnt
    int* cnt = (int*)d_ws;
    int* scnt = cnt + nCnt;

    const size_t survSlots = (size_t)BIMG * NCLS * NSURV;   // 72800
    float* SX1 = (float*)((char*)d_ws + 49504);
    float* SY1 = SX1 + survSlots;
    float* SX2 = SY1 + survSlots;
    float* SY2 = SX2 + survSlots;
    float* SS  = SY2 + survSlots;
    int*   SIDX = (int*)(SS + survSlots);

    const size_t clBase = 49504 + survSlots * 6 * 4;         // 1,796,704
    long capC = 256;
    if (ws_size > clBase) {
        capC = (long)((ws_size - clBase) / ((size_t)BIMG * NCLS * 24));
        capC &= ~63L;
        if (capC < 256) capC = 256;
        if (capC > MAXK) capC = MAXK;
    }
    const size_t clSlots = (size_t)BIMG * NCLS * capC;
    float* CX1 = (float*)((char*)d_ws + clBase);
    float* CY1 = CX1 + clSlots;
    float* CX2 = CY1 + clSlots;
    float* CY2 = CX2 + clSlots;
    float* CS  = CY2 + clSlots;
    int*   CIDX = (int*)(CS + clSlots);

    zero_kernel<<<(nZero + 255) / 256, 256, 0, stream>>>(cnt, nZero);
    decode_kernel<<<BIMG * NPROP / 4, 256, 0, stream>>>(
        logits, creg, props, CX1, CY1, CX2, CY2, CS, CIDX, cnt, (int)capC);
    nms_class_kernel<<<BIMG * NCLS, 256, 0, stream>>>(
        CX1, CY1, CX2, CY2, CS, CIDX, cnt,
        SX1, SY1, SX2, SY2, SS, SIDX, scnt, (int)capC);
    merge_kernel<<<BIMG, 256, 0, stream>>>(
        SX1, SY1, SX2, SY2, SS, SIDX, scnt, out);
}

// Round 4
// 406.307 us; speedup vs baseline: 7.9438x; 1.2111x over previous
//
#include <hip/hip_runtime.h>

// RoIHeads postprocess: decode + softmax + filter + per-class NMS (sort +
// triangular suppression matrix + register bitmask scan) + histogram top-k.
// B=8 images, N=8192 proposals, C=91 classes (class 0 = background dropped).
#define BIMG 8
#define NPROP 8192
#define NCLS 91
#define WIMG 800.0f
#define HIMG 800.0f
#define SCORE_T 0.05f
#define NMS_T 0.5f
#define NDET 100
#define CLIPV 4.135166556742356f   // float(log(1000/16))
#define CNT_STRIDE 16              // 64B-padded per-(b,c) counters
#define NSURV 100                  // per-class survivor cap
#define MAXK 512                   // per-(b,c) candidate cap (measured ~215)
#define NBUCK 1024                 // merge histogram buckets (<=576 used)
#define MAXTIE 256

__device__ __forceinline__ unsigned long long packkey(float s, unsigned int idx) {
    // s > 0 always; higher score wins, then smaller flat index wins.
    return ((unsigned long long)__float_as_uint(s) << 32) |
           (unsigned long long)(0xFFFFFFFFu - idx);
}

// ---------------- kernel 0: zero counters (cnt + scnt, contiguous) ---------
__global__ void zero_kernel(int* p, int n) {
    int i = blockIdx.x * blockDim.x + threadIdx.x;
    if (i < n) p[i] = 0;
}

// ---------------- kernel 1: decode + softmax + filter, bin by (b,c) --------
// One wave (64 lanes) per proposal row. Lane l owns classes {l, l+64}.
__global__ __launch_bounds__(256)
void decode_kernel(const float* __restrict__ logits,
                   const float* __restrict__ creg,
                   const float* __restrict__ props,
                   float4* __restrict__ CBOX,
                   unsigned long long* __restrict__ CKEY,
                   int* __restrict__ cnt, int capC)
{
    const int wave = blockIdx.x * 4 + (threadIdx.x >> 6);
    const int lane = threadIdx.x & 63;
    const int row = wave;                 // 0 .. B*N-1
    const int b = row >> 13;              // /NPROP
    const int n = row & (NPROP - 1);

    const float* lrow = logits + (size_t)row * NCLS;
    const float l0 = lrow[lane];                                   // lane<91 always
    const float l1 = (lane + 64 < NCLS) ? lrow[lane + 64] : -3.4e38f;

    float m = fmaxf(l0, l1);
    for (int mm = 32; mm > 0; mm >>= 1) m = fmaxf(m, __shfl_xor(m, mm));

    const float e0 = expf(l0 - m);
    const float e1 = (lane + 64 < NCLS) ? expf(l1 - m) : 0.0f;

    float s = e0 + e1;
    for (int mm = 32; mm > 0; mm >>= 1) s += __shfl_xor(s, mm);
    const float denom = __shfl(s, 0);     // identical denom for all classes

    const float4 p4 = ((const float4*)props)[row];   // uniform -> scalar load
    const float w = p4.z - p4.x, h = p4.w - p4.y;
    const float cx = p4.x + 0.5f * w, cy = p4.y + 0.5f * h;

    for (int half = 0; half < 2; ++half) {
        const int c = lane + half * 64;
        if (c < 1 || c >= NCLS) continue;
        const float score = (half ? e1 : e0) / denom;
        if (!(score > SCORE_T)) continue;

        const float4 cd = ((const float4*)creg)[(size_t)row * NCLS + c];
        const float dx = cd.x / 10.0f;
        const float dy = cd.y / 10.0f;
        const float dw = fminf(cd.z / 5.0f, CLIPV);
        const float dh = fminf(cd.w / 5.0f, CLIPV);
        const float pcx = dx * w + cx, pcy = dy * h + cy;
        const float pw = expf(dw) * w, ph = expf(dh) * h;
        float bx1 = pcx - 0.5f * pw, by1 = pcy - 0.5f * ph;
        float bx2 = pcx + 0.5f * pw, by2 = pcy + 0.5f * ph;
        bx1 = fminf(fmaxf(bx1, 0.0f), WIMG);
        by1 = fminf(fmaxf(by1, 0.0f), HIMG);
        bx2 = fminf(fmaxf(bx2, 0.0f), WIMG);
        by2 = fminf(fmaxf(by2, 0.0f), HIMG);
        if ((bx2 - bx1) >= 1.0f && (by2 - by1) >= 1.0f) {
            const int bc = b * NCLS + c;
            const int k = atomicAdd(&cnt[bc * CNT_STRIDE], 1);
            if (k < capC) {
                const size_t o = (size_t)bc * capC + k;
                CBOX[o] = make_float4(bx1, by1, bx2, by2);
                CKEY[o] = packkey(score, (unsigned int)(n * (NCLS - 1) + (c - 1)));
            }
        }
    }
}

// ---------------- kernel 2: per-(image,class) NMS, one 256-thr block -------
// sort by key desc -> upper-triangle IoU matrix -> register bitmask scan.
__global__ __launch_bounds__(256)
void nms_class_kernel(const float4* __restrict__ CBOX,
                      const unsigned long long* __restrict__ CKEY,
                      const int* __restrict__ cnt,
                      float4* __restrict__ SBOX,
                      unsigned long long* __restrict__ SKEY,
                      int* __restrict__ scnt, int capC)
{
    const int bc = blockIdx.x;           // b*91 + c
    const int c = bc % NCLS;
    const int tid = threadIdx.x;
    const int lane = tid & 63;
    const int wv = tid >> 6;

    int K = 0;
    if (c != 0) {
        K = cnt[bc * CNT_STRIDE];
        if (K > capC) K = capC;
        if (K > MAXK) K = MAXK;
    }
    if (K == 0) { if (tid == 0) scnt[bc] = 0; return; }

    __shared__ float4 sbox[MAXK];                         // 8 KB
    __shared__ unsigned long long skey[MAXK];             // 4 KB
    __shared__ __align__(16) unsigned long long mask[MAXK * 8];  // 32 KB; also sort tmp
    __shared__ int wseq[NSURV];
    __shared__ int nselsh;

    const size_t base = (size_t)bc * capC;
    for (int i = tid; i < K; i += 256) {
        sbox[i] = CBOX[base + i];
        skey[i] = CKEY[base + i];
    }
    __syncthreads();

    // rank-sort (unique keys -> exact descending order) via tmp in mask region
    float4* tb = (float4*)mask;                                       // 8 KB
    unsigned long long* tk = (unsigned long long*)((char*)mask + MAXK * 16);
    for (int i = tid; i < K; i += 256) {
        const unsigned long long k = skey[i];
        int r = 0;
        for (int j = 0; j < K; ++j) r += (skey[j] > k) ? 1 : 0;
        tb[r] = sbox[i]; tk[r] = k;
    }
    __syncthreads();
    for (int i = tid; i < K; i += 256) { sbox[i] = tb[i]; skey[i] = tk[i]; }
    __syncthreads();
    for (int i = tid; i < K * 8; i += 256) mask[i] = 0ull;
    __syncthreads();

    // upper-triangle suppression matrix: bit (a, j) for j > a only; when a is
    // selected all ranks < a are provably dead. Reference IoU arithmetic in
    // offset space. Wave wv owns 64-wide column strip(s) w.
    const float off = (float)c * 801.0f;     // max(H,W)+1 per-class offset
    const int W = (K + 63) >> 6;
    for (int w = wv; w < W; w += 4) {
        const int j = (w << 6) + lane;
        const bool jv = (j < K);
        float jx1 = 0, jy1 = 0, jx2 = 0, jy2 = 0;
        if (jv) {
            const float4 bj = sbox[j];
            jx1 = bj.x + off; jy1 = bj.y + off;
            jx2 = bj.z + off; jy2 = bj.w + off;
        }
        const float a2 = (jx2 - jx1) * (jy2 - jy1);
        const int aend = min(K, (w + 1) << 6);
        for (int a = 0; a < aend; ++a) {
            const float4 ba = sbox[a];
            const float ax1 = ba.x + off, ay1 = ba.y + off;
            const float ax2 = ba.z + off, ay2 = ba.w + off;
            const float ta = (ax2 - ax1) * (ay2 - ay1);
            bool sup = false;
            if (jv && j > a) {
                const float ltx = fmaxf(ax1, jx1), lty = fmaxf(ay1, jy1);
                const float rbx = fminf(ax2, jx2), rby = fminf(ay2, jy2);
                const float iw = fmaxf(rbx - ltx, 0.0f);
                const float ih = fmaxf(rby - lty, 0.0f);
                const float inter = iw * ih;
                const float iou = inter / (ta + a2 - inter + 1e-9f);
                sup = iou > NMS_T;
            }
            const unsigned long long bal = __ballot(sup);
            if (lane == 0) mask[a * 8 + w] = bal;
        }
    }
    __syncthreads();

    // greedy scan: alive mask fully in VGPRs (redundant across wave-0 lanes);
    // per step: pure-VALU find-first-set + one broadcast 64B LDS row read.
    if (wv == 0) {
        unsigned long long aw[8];
        #pragma unroll
        for (int w = 0; w < 8; ++w) {
            const int lo = w << 6;
            aw[w] = (K > lo) ? ((K - lo >= 64) ? ~0ull : ((1ull << (K - lo)) - 1ull))
                             : 0ull;
        }
        int nsel = 0;
        while (nsel < NSURV) {
            int pos = -1;
            #pragma unroll
            for (int w = 0; w < 8; ++w)
                if (pos < 0 && aw[w]) pos = (w << 6) + __builtin_ctzll(aw[w]);
            if (pos < 0) break;
            if (lane == 0) wseq[nsel] = pos;
            const unsigned long long* mrow = &mask[(size_t)pos * 8];
            #pragma unroll
            for (int w = 0; w < 8; ++w) aw[w] &= ~mrow[w];
            aw[pos >> 6] &= ~(1ull << (pos & 63));   // self-suppress
            ++nsel;
        }
        if (lane == 0) nselsh = nsel;
    }
    __syncthreads();

    const int nsel = nselsh;
    for (int t = tid; t < nsel; t += 256) {
        const int a = wseq[t];
        SBOX[bc * NSURV + t] = sbox[a];
        SKEY[bc * NSURV + t] = skey[a];
    }
    if (tid == 0) scnt[bc] = nsel;
}

// ---------------- kernel 3: exact global top-100 via histogram select ------
// Output = top-NDET keys of the survivor union, descending (keys unique).
__global__ __launch_bounds__(1024)
void merge_kernel(const float4* __restrict__ SBOX,
                  const unsigned long long* __restrict__ SKEY,
                  const int* __restrict__ scnt, float* __restrict__ out)
{
    const int b = blockIdx.x;
    const int tid = threadIdx.x;

    __shared__ int scs[NCLS];
    __shared__ unsigned int hist[NBUCK];
    __shared__ unsigned long long selk[NDET];
    __shared__ int seli[NDET];
    __shared__ unsigned long long tiek[MAXTIE];
    __shared__ int tiei[MAXTIE];
    __shared__ int selc, tiec, Tsh;

    if (tid < NCLS) scs[tid] = scnt[b * NCLS + tid];
    for (int i = tid; i < NBUCK; i += 1024) hist[i] = 0u;
    if (tid == 0) { selc = 0; tiec = 0; Tsh = -1; }
    __syncthreads();

    // pass 1: histogram on score bits (scores in (0.05, 1) -> buckets < 576)
    for (int t = tid; t < NCLS * NSURV; t += 1024) {
        const int cc = t / NSURV, j = t % NSURV;
        if (cc >= 1 && j < scs[cc]) {
            const unsigned long long k = SKEY[(size_t)b * NCLS * NSURV + t];
            const unsigned int sb32 = (unsigned int)(k >> 32);
            int bk = (int)((sb32 - 0x3D400000u) >> 16);
            bk = max(0, min(NBUCK - 1, bk));
            atomicAdd(&hist[bk], 1u);
        }
    }
    __syncthreads();

    // inclusive suffix scan: hist[t] = count of keys in buckets >= t
    for (int off2 = 1; off2 < NBUCK; off2 <<= 1) {
        const unsigned int v = (tid + off2 < NBUCK) ? hist[tid + off2] : 0u;
        __syncthreads();
        hist[tid] += v;
        __syncthreads();
    }

    // threshold bucket T = max t with suffix(t) > NDET (or -1)
    {
        const unsigned int g = hist[tid];
        const unsigned int g1 = (tid + 1 < NBUCK) ? hist[tid + 1] : 0u;
        if (g > (unsigned)NDET && g1 <= (unsigned)NDET) Tsh = tid;
    }
    __syncthreads();
    const int T = Tsh;
    const int S = (int)hist[0];
    const int M = min(NDET, S);
    const int A = (T + 1 < NBUCK) ? (int)hist[T + 1] : 0;   // sure selections
    const int need = M - A;                                 // taken from bucket T

    // pass 2: collect sure (bucket > T) and tie (bucket == T) candidates
    for (int t = tid; t < NCLS * NSURV; t += 1024) {
        const int cc = t / NSURV, j = t % NSURV;
        if (cc >= 1 && j < scs[cc]) {
            const int sb = b * NCLS * NSURV + t;
            const unsigned long long k = SKEY[sb];
            const unsigned int sb32 = (unsigned int)(k >> 32);
            int bk = (int)((sb32 - 0x3D400000u) >> 16);
            bk = max(0, min(NBUCK - 1, bk));
            if (bk > T) {
                const int p = atomicAdd(&selc, 1);
                if (p < NDET) { selk[p] = k; seli[p] = sb; }
            } else if (bk == T) {
                const int q = atomicAdd(&tiec, 1);
                if (q < MAXTIE) { tiek[q] = k; tiei[q] = sb; }
            }
        }
    }
    __syncthreads();

    // rank ties, append the top-`need` of them (always enough ties exist)
    const int nt = min(tiec, MAXTIE);
    for (int q = tid; q < nt; q += 1024) {
        const unsigned long long k = tiek[q];
        int r = 0;
        for (int j2 = 0; j2 < nt; ++j2) r += (tiek[j2] > k) ? 1 : 0;
        if (r < need) { selk[A + r] = k; seli[A + r] = tiei[q]; }
    }
    __syncthreads();

    // final exact rank-sort of the M selected; write outputs at rank
    const int OB = 0, OS = BIMG * NDET * 4, OL = OS + BIMG * NDET,
              OV = OL + BIMG * NDET;
    for (int mi = tid; mi < M; mi += 1024) {
        const unsigned long long k = selk[mi];
        int r = 0;
        for (int j2 = 0; j2 < M; ++j2) r += (selk[j2] > k) ? 1 : 0;
        const float4 bx = SBOX[seli[mi]];
        const int o = b * NDET + r;
        out[OB + o * 4 + 0] = bx.x; out[OB + o * 4 + 1] = bx.y;
        out[OB + o * 4 + 2] = bx.z; out[OB + o * 4 + 3] = bx.w;
        const unsigned int idx = 0xFFFFFFFFu - (unsigned int)k;
        out[OS + o] = __uint_as_float((unsigned int)(k >> 32));
        out[OL + o] = (float)((int)(idx % (NCLS - 1)) + 1);
        out[OV + o] = 1.0f;
    }
    for (int mi = M + tid; mi < NDET; mi += 1024) {
        const int o = b * NDET + mi;
        out[OB + o * 4 + 0] = 0.0f; out[OB + o * 4 + 1] = 0.0f;
        out[OB + o * 4 + 2] = 0.0f; out[OB + o * 4 + 3] = 0.0f;
        out[OS + o] = 0.0f; out[OL + o] = 0.0f; out[OV + o] = 0.0f;
    }
}

extern "C" void kernel_launch(void* const* d_in, const int* in_sizes, int n_in,
                              void* d_out, int out_size, void* d_ws, size_t ws_size,
                              hipStream_t stream) {
    const float* logits = (const float*)d_in[0];   // [B,N,91]
    const float* creg   = (const float*)d_in[1];   // [B,N,364]
    const float* props  = (const float*)d_in[2];   // [B,N,4]
    float* out = (float*)d_out;                    // 3200+800+800+800 floats

    // ---- workspace layout ----
    // [0)        cnt  : 8*91*16 ints (64B-padded counters)       46592 B
    // [46592)    scnt : 8*91 ints                                 2912 B
    // [49504)    SBOX : 8*91*100 float4                        1164800 B
    // [1214304)  SKEY : 8*91*100 u64                            582400 B
    // [1796704)  CBOX/CKEY: (8*91*capC) x (16+8) B
    const int nCnt = BIMG * NCLS * CNT_STRIDE;
    const int nZero = nCnt + BIMG * NCLS;
    int* cnt = (int*)d_ws;
    int* scnt = cnt + nCnt;

    const size_t survSlots = (size_t)BIMG * NCLS * NSURV;   // 72800
    float4* SBOX = (float4*)((char*)d_ws + 49504);
    unsigned long long* SKEY = (unsigned long long*)(SBOX + survSlots);

    const size_t clBase = 49504 + survSlots * 24;           // 1,796,704
    long capC = 256;
    if (ws_size > clBase) {
        capC = (long)((ws_size - clBase) / ((size_t)BIMG * NCLS * 24));
        capC &= ~63L;
        if (capC < 256) capC = 256;
        if (capC > MAXK) capC = MAXK;
    }
    const size_t clSlots = (size_t)BIMG * NCLS * capC;
    float4* CBOX = (float4*)((char*)d_ws + clBase);
    unsigned long long* CKEY = (unsigned long long*)(CBOX + clSlots);

    zero_kernel<<<(nZero + 255) / 256, 256, 0, stream>>>(cnt, nZero);
    decode_kernel<<<BIMG * NPROP / 4, 256, 0, stream>>>(
        logits, creg, props, CBOX, CKEY, cnt, (int)capC);
    nms_class_kernel<<<BIMG * NCLS, 256, 0, stream>>>(
        CBOX, CKEY, cnt, SBOX, SKEY, scnt, (int)capC);
    merge_kernel<<<BIMG, 1024, 0, stream>>>(SBOX, SKEY, scnt, out);
}

// Round 5
// 398.579 us; speedup vs baseline: 8.0978x; 1.0194x over previous
//
#include <hip/hip_runtime.h>

// RoIHeads postprocess: decode + softmax + filter + per-class NMS (sort +
// triangular suppression matrix + register bitmask scan) + histogram top-k.
// B=8 images, N=8192 proposals, C=91 classes (class 0 = background dropped).
#define BIMG 8
#define NPROP 8192
#define NCLS 91
#define WIMG 800.0f
#define HIMG 800.0f
#define SCORE_T 0.05f
#define NMS_T 0.5f
#define NDET 100
#define CLIPV 4.135166556742356f   // float(log(1000/16))
#define CNT_STRIDE 16              // 64B-padded per-(b,c) counters
#define NSURV 100                  // per-class survivor cap
#define MAXK 512                   // per-(b,c) candidate cap (measured ~215)
#define NBUCK 1024                 // merge histogram buckets (<=576 used)
#define MAXTIE 256

__device__ __forceinline__ unsigned long long packkey(float s, unsigned int idx) {
    // s > 0 always; higher score wins, then smaller flat index wins.
    return ((unsigned long long)__float_as_uint(s) << 32) |
           (unsigned long long)(0xFFFFFFFFu - idx);
}

// ---------------- kernel 0: zero counters (cnt + scnt, contiguous) ---------
__global__ void zero_kernel(int* p, int n) {
    int i = blockIdx.x * blockDim.x + threadIdx.x;
    if (i < n) p[i] = 0;
}

// ---------------- kernel 1: decode + softmax + filter, bin by (b,c) --------
// One wave (64 lanes) per proposal row. Lane l owns classes {l, l+64}.
__global__ __launch_bounds__(256)
void decode_kernel(const float* __restrict__ logits,
                   const float* __restrict__ creg,
                   const float* __restrict__ props,
                   float4* __restrict__ CBOX,
                   unsigned long long* __restrict__ CKEY,
                   int* __restrict__ cnt, int capC)
{
    const int wave = blockIdx.x * 4 + (threadIdx.x >> 6);
    const int lane = threadIdx.x & 63;
    const int row = wave;                 // 0 .. B*N-1
    const int b = row >> 13;              // /NPROP
    const int n = row & (NPROP - 1);

    const float* lrow = logits + (size_t)row * NCLS;
    const float l0 = lrow[lane];                                   // lane<91 always
    const float l1 = (lane + 64 < NCLS) ? lrow[lane + 64] : -3.4e38f;

    float m = fmaxf(l0, l1);
    for (int mm = 32; mm > 0; mm >>= 1) m = fmaxf(m, __shfl_xor(m, mm));

    const float e0 = expf(l0 - m);
    const float e1 = (lane + 64 < NCLS) ? expf(l1 - m) : 0.0f;

    float s = e0 + e1;
    for (int mm = 32; mm > 0; mm >>= 1) s += __shfl_xor(s, mm);
    const float denom = __shfl(s, 0);     // identical denom for all classes

    const float4 p4 = ((const float4*)props)[row];   // uniform -> scalar load
    const float w = p4.z - p4.x, h = p4.w - p4.y;
    const float cx = p4.x + 0.5f * w, cy = p4.y + 0.5f * h;

    for (int half = 0; half < 2; ++half) {
        const int c = lane + half * 64;
        if (c < 1 || c >= NCLS) continue;
        const float score = (half ? e1 : e0) / denom;
        if (!(score > SCORE_T)) continue;

        const float4 cd = ((const float4*)creg)[(size_t)row * NCLS + c];
        const float dx = cd.x / 10.0f;
        const float dy = cd.y / 10.0f;
        const float dw = fminf(cd.z / 5.0f, CLIPV);
        const float dh = fminf(cd.w / 5.0f, CLIPV);
        const float pcx = dx * w + cx, pcy = dy * h + cy;
        const float pw = expf(dw) * w, ph = expf(dh) * h;
        float bx1 = pcx - 0.5f * pw, by1 = pcy - 0.5f * ph;
        float bx2 = pcx + 0.5f * pw, by2 = pcy + 0.5f * ph;
        bx1 = fminf(fmaxf(bx1, 0.0f), WIMG);
        by1 = fminf(fmaxf(by1, 0.0f), HIMG);
        bx2 = fminf(fmaxf(bx2, 0.0f), WIMG);
        by2 = fminf(fmaxf(by2, 0.0f), HIMG);
        if ((bx2 - bx1) >= 1.0f && (by2 - by1) >= 1.0f) {
            const int bc = b * NCLS + c;
            const int k = atomicAdd(&cnt[bc * CNT_STRIDE], 1);
            if (k < capC) {
                const size_t o = (size_t)bc * capC + k;
                CBOX[o] = make_float4(bx1, by1, bx2, by2);
                CKEY[o] = packkey(score, (unsigned int)(n * (NCLS - 1) + (c - 1)));
            }
        }
    }
}

// ---------------- kernel 2: per-(image,class) NMS, one 256-thr block -------
// sort by key desc -> upper-triangle IoU matrix -> register bitmask scan.
__global__ __launch_bounds__(256)
void nms_class_kernel(const float4* __restrict__ CBOX,
                      const unsigned long long* __restrict__ CKEY,
                      const int* __restrict__ cnt,
                      float4* __restrict__ SBOX,
                      unsigned long long* __restrict__ SKEY,
                      int* __restrict__ scnt, int capC)
{
    const int bc = blockIdx.x;           // b*91 + c
    const int c = bc % NCLS;
    const int tid = threadIdx.x;
    const int lane = tid & 63;
    const int wv = tid >> 6;

    int K = 0;
    if (c != 0) {
        K = cnt[bc * CNT_STRIDE];
        if (K > capC) K = capC;
        if (K > MAXK) K = MAXK;
    }
    if (K == 0) { if (tid == 0) scnt[bc] = 0; return; }

    __shared__ float4 sbox[MAXK];                         // 8 KB
    __shared__ unsigned long long skey[MAXK];             // 4 KB
    __shared__ __align__(16) unsigned long long mask[MAXK * 8];  // 32 KB; also sort tmp
    __shared__ int wseq[NSURV];
    __shared__ int nselsh;

    const size_t base = (size_t)bc * capC;
    for (int i = tid; i < K; i += 256) {
        sbox[i] = CBOX[base + i];
        skey[i] = CKEY[base + i];
    }
    __syncthreads();

    // rank-sort (unique keys -> exact descending order) via tmp in mask region
    float4* tb = (float4*)mask;                                       // 8 KB
    unsigned long long* tk = (unsigned long long*)((char*)mask + MAXK * 16);
    for (int i = tid; i < K; i += 256) {
        const unsigned long long k = skey[i];
        int r = 0;
        for (int j = 0; j < K; ++j) r += (skey[j] > k) ? 1 : 0;
        tb[r] = sbox[i]; tk[r] = k;
    }
    __syncthreads();
    for (int i = tid; i < K; i += 256) { sbox[i] = tb[i]; skey[i] = tk[i]; }
    __syncthreads();
    for (int i = tid; i < K * 8; i += 256) mask[i] = 0ull;
    __syncthreads();

    // upper-triangle suppression matrix: bit (a, j) for j > a only; when a is
    // selected all ranks < a are provably dead. Reference IoU arithmetic in
    // offset space. Wave wv owns 64-wide column strip(s) w.
    const float off = (float)c * 801.0f;     // max(H,W)+1 per-class offset
    const int W = (K + 63) >> 6;
    for (int w = wv; w < W; w += 4) {
        const int j = (w << 6) + lane;
        const bool jv = (j < K);
        float jx1 = 0, jy1 = 0, jx2 = 0, jy2 = 0;
        if (jv) {
            const float4 bj = sbox[j];
            jx1 = bj.x + off; jy1 = bj.y + off;
            jx2 = bj.z + off; jy2 = bj.w + off;
        }
        const float a2 = (jx2 - jx1) * (jy2 - jy1);
        const int aend = min(K, (w + 1) << 6);
        for (int a = 0; a < aend; ++a) {
            const float4 ba = sbox[a];
            const float ax1 = ba.x + off, ay1 = ba.y + off;
            const float ax2 = ba.z + off, ay2 = ba.w + off;
            const float ta = (ax2 - ax1) * (ay2 - ay1);
            bool sup = false;
            if (jv && j > a) {
                const float ltx = fmaxf(ax1, jx1), lty = fmaxf(ay1, jy1);
                const float rbx = fminf(ax2, jx2), rby = fminf(ay2, jy2);
                const float iw = fmaxf(rbx - ltx, 0.0f);
                const float ih = fmaxf(rby - lty, 0.0f);
                const float inter = iw * ih;
                const float iou = inter / (ta + a2 - inter + 1e-9f);
                sup = iou > NMS_T;
            }
            const unsigned long long bal = __ballot(sup);
            if (lane == 0) mask[a * 8 + w] = bal;
        }
    }
    __syncthreads();

    // greedy scan: alive mask in 8 NAMED u64 VGPRs (redundant across wave-0
    // lanes). All indexing is compile-time-static -> no scratch (rule #20:
    // runtime-indexed register arrays spill to scratch; that cost 200us in r4).
    if (wv == 0) {
        unsigned long long aw0, aw1, aw2, aw3, aw4, aw5, aw6, aw7;
#define AWINIT(w) ((K > ((w) << 6)) \
        ? ((K - ((w) << 6) >= 64) ? ~0ull : ((1ull << (K - ((w) << 6))) - 1ull)) \
        : 0ull)
        aw0 = AWINIT(0); aw1 = AWINIT(1); aw2 = AWINIT(2); aw3 = AWINIT(3);
        aw4 = AWINIT(4); aw5 = AWINIT(5); aw6 = AWINIT(6); aw7 = AWINIT(7);
#undef AWINIT
        int nsel = 0;
        while (nsel < NSURV) {
            int pos = -1;
            if      (aw0) pos =   0 + __builtin_ctzll(aw0);
            else if (aw1) pos =  64 + __builtin_ctzll(aw1);
            else if (aw2) pos = 128 + __builtin_ctzll(aw2);
            else if (aw3) pos = 192 + __builtin_ctzll(aw3);
            else if (aw4) pos = 256 + __builtin_ctzll(aw4);
            else if (aw5) pos = 320 + __builtin_ctzll(aw5);
            else if (aw6) pos = 384 + __builtin_ctzll(aw6);
            else if (aw7) pos = 448 + __builtin_ctzll(aw7);
            if (pos < 0) break;
            if (lane == 0) wseq[nsel] = pos;
            const unsigned long long* mrow = &mask[(size_t)pos * 8];
            const int pw = pos >> 6;
            const unsigned long long pb = 1ull << (pos & 63);
            unsigned long long m0 = mrow[0]; if (pw == 0) m0 |= pb; aw0 &= ~m0;
            unsigned long long m1 = mrow[1]; if (pw == 1) m1 |= pb; aw1 &= ~m1;
            unsigned long long m2 = mrow[2]; if (pw == 2) m2 |= pb; aw2 &= ~m2;
            unsigned long long m3 = mrow[3]; if (pw == 3) m3 |= pb; aw3 &= ~m3;
            unsigned long long m4 = mrow[4]; if (pw == 4) m4 |= pb; aw4 &= ~m4;
            unsigned long long m5 = mrow[5]; if (pw == 5) m5 |= pb; aw5 &= ~m5;
            unsigned long long m6 = mrow[6]; if (pw == 6) m6 |= pb; aw6 &= ~m6;
            unsigned long long m7 = mrow[7]; if (pw == 7) m7 |= pb; aw7 &= ~m7;
            ++nsel;
        }
        if (lane == 0) nselsh = nsel;
    }
    __syncthreads();

    const int nsel = nselsh;
    for (int t = tid; t < nsel; t += 256) {
        const int a = wseq[t];
        SBOX[bc * NSURV + t] = sbox[a];
        SKEY[bc * NSURV + t] = skey[a];
    }
    if (tid == 0) scnt[bc] = nsel;
}

// ---------------- kernel 3: exact global top-100 via histogram select ------
// Output = top-NDET keys of the survivor union, descending (keys unique).
__global__ __launch_bounds__(1024)
void merge_kernel(const float4* __restrict__ SBOX,
                  const unsigned long long* __restrict__ SKEY,
                  const int* __restrict__ scnt, float* __restrict__ out)
{
    const int b = blockIdx.x;
    const int tid = threadIdx.x;

    __shared__ int scs[NCLS];
    __shared__ unsigned int hist[NBUCK];
    __shared__ unsigned long long selk[NDET];
    __shared__ int seli[NDET];
    __shared__ unsigned long long tiek[MAXTIE];
    __shared__ int tiei[MAXTIE];
    __shared__ int selc, tiec, Tsh;

    if (tid < NCLS) scs[tid] = scnt[b * NCLS + tid];
    for (int i = tid; i < NBUCK; i += 1024) hist[i] = 0u;
    if (tid == 0) { selc = 0; tiec = 0; Tsh = -1; }
    __syncthreads();

    // pass 1: histogram on score bits (scores in (0.05, 1) -> buckets < 576)
    for (int t = tid; t < NCLS * NSURV; t += 1024) {
        const int cc = t / NSURV, j = t % NSURV;
        if (cc >= 1 && j < scs[cc]) {
            const unsigned long long k = SKEY[(size_t)b * NCLS * NSURV + t];
            const unsigned int sb32 = (unsigned int)(k >> 32);
            int bk = (int)((sb32 - 0x3D400000u) >> 16);
            bk = max(0, min(NBUCK - 1, bk));
            atomicAdd(&hist[bk], 1u);
        }
    }
    __syncthreads();

    // inclusive suffix scan: hist[t] = count of keys in buckets >= t
    for (int off2 = 1; off2 < NBUCK; off2 <<= 1) {
        const unsigned int v = (tid + off2 < NBUCK) ? hist[tid + off2] : 0u;
        __syncthreads();
        hist[tid] += v;
        __syncthreads();
    }

    // threshold bucket T = max t with suffix(t) > NDET (or -1)
    {
        const unsigned int g = hist[tid];
        const unsigned int g1 = (tid + 1 < NBUCK) ? hist[tid + 1] : 0u;
        if (g > (unsigned)NDET && g1 <= (unsigned)NDET) Tsh = tid;
    }
    __syncthreads();
    const int T = Tsh;
    const int S = (int)hist[0];
    const int M = min(NDET, S);
    const int A = (T + 1 < NBUCK) ? (int)hist[T + 1] : 0;   // sure selections
    const int need = M - A;                                 // taken from bucket T

    // pass 2: collect sure (bucket > T) and tie (bucket == T) candidates
    for (int t = tid; t < NCLS * NSURV; t += 1024) {
        const int cc = t / NSURV, j = t % NSURV;
        if (cc >= 1 && j < scs[cc]) {
            const int sb = b * NCLS * NSURV + t;
            const unsigned long long k = SKEY[sb];
            const unsigned int sb32 = (unsigned int)(k >> 32);
            int bk = (int)((sb32 - 0x3D400000u) >> 16);
            bk = max(0, min(NBUCK - 1, bk));
            if (bk > T) {
                const int p = atomicAdd(&selc, 1);
                if (p < NDET) { selk[p] = k; seli[p] = sb; }
            } else if (bk == T) {
                const int q = atomicAdd(&tiec, 1);
                if (q < MAXTIE) { tiek[q] = k; tiei[q] = sb; }
            }
        }
    }
    __syncthreads();

    // rank ties, append the top-`need` of them (always enough ties exist)
    const int nt = min(tiec, MAXTIE);
    for (int q = tid; q < nt; q += 1024) {
        const unsigned long long k = tiek[q];
        int r = 0;
        for (int j2 = 0; j2 < nt; ++j2) r += (tiek[j2] > k) ? 1 : 0;
        if (r < need) { selk[A + r] = k; seli[A + r] = tiei[q]; }
    }
    __syncthreads();

    // final exact rank-sort of the M selected; write outputs at rank
    const int OB = 0, OS = BIMG * NDET * 4, OL = OS + BIMG * NDET,
              OV = OL + BIMG * NDET;
    for (int mi = tid; mi < M; mi += 1024) {
        const unsigned long long k = selk[mi];
        int r = 0;
        for (int j2 = 0; j2 < M; ++j2) r += (selk[j2] > k) ? 1 : 0;
        const float4 bx = SBOX[seli[mi]];
        const int o = b * NDET + r;
        out[OB + o * 4 + 0] = bx.x; out[OB + o * 4 + 1] = bx.y;
        out[OB + o * 4 + 2] = bx.z; out[OB + o * 4 + 3] = bx.w;
        const unsigned int idx = 0xFFFFFFFFu - (unsigned int)k;
        out[OS + o] = __uint_as_float((unsigned int)(k >> 32));
        out[OL + o] = (float)((int)(idx % (NCLS - 1)) + 1);
        out[OV + o] = 1.0f;
    }
    for (int mi = M + tid; mi < NDET; mi += 1024) {
        const int o = b * NDET + mi;
        out[OB + o * 4 + 0] = 0.0f; out[OB + o * 4 + 1] = 0.0f;
        out[OB + o * 4 + 2] = 0.0f; out[OB + o * 4 + 3] = 0.0f;
        out[OS + o] = 0.0f; out[OL + o] = 0.0f; out[OV + o] = 0.0f;
    }
}

extern "C" void kernel_launch(void* const* d_in, const int* in_sizes, int n_in,
                              void* d_out, int out_size, void* d_ws, size_t ws_size,
                              hipStream_t stream) {
    const float* logits = (const float*)d_in[0];   // [B,N,91]
    const float* creg   = (const float*)d_in[1];   // [B,N,364]
    const float* props  = (const float*)d_in[2];   // [B,N,4]
    float* out = (float*)d_out;                    // 3200+800+800+800 floats

    // ---- workspace layout ----
    // [0)        cnt  : 8*91*16 ints (64B-padded counters)       46592 B
    // [46592)    scnt : 8*91 ints                                 2912 B
    // [49504)    SBOX : 8*91*100 float4                        1164800 B
    // [1214304)  SKEY : 8*91*100 u64                            582400 B
    // [1796704)  CBOX/CKEY: (8*91*capC) x (16+8) B
    const int nCnt = BIMG * NCLS * CNT_STRIDE;
    const int nZero = nCnt + BIMG * NCLS;
    int* cnt = (int*)d_ws;
    int* scnt = cnt + nCnt;

    const size_t survSlots = (size_t)BIMG * NCLS * NSURV;   // 72800
    float4* SBOX = (float4*)((char*)d_ws + 49504);
    unsigned long long* SKEY = (unsigned long long*)(SBOX + survSlots);

    const size_t clBase = 49504 + survSlots * 24;           // 1,796,704
    long capC = 256;
    if (ws_size > clBase) {
        capC = (long)((ws_size - clBase) / ((size_t)BIMG * NCLS * 24));
        capC &= ~63L;
        if (capC < 256) capC = 256;
        if (capC > MAXK) capC = MAXK;
    }
    const size_t clSlots = (size_t)BIMG * NCLS * capC;
    float4* CBOX = (float4*)((char*)d_ws + clBase);
    unsigned long long* CKEY = (unsigned long long*)(CBOX + clSlots);

    zero_kernel<<<(nZero + 255) / 256, 256, 0, stream>>>(cnt, nZero);
    decode_kernel<<<BIMG * NPROP / 4, 256, 0, stream>>>(
        logits, creg, props, CBOX, CKEY, cnt, (int)capC);
    nms_class_kernel<<<BIMG * NCLS, 256, 0, stream>>>(
        CBOX, CKEY, cnt, SBOX, SKEY, scnt, (int)capC);
    merge_kernel<<<BIMG, 1024, 0, stream>>>(SBOX, SKEY, scnt, out);
}